// Round 1
// baseline (795.468 us; speedup 1.0000x reference)
//
#include <hip/hip_runtime.h>
#include <cstdint>

// Problem geometry (fixed by the reference)
#define D_IN   4096
#define D_OUT  4096
#define MTOT   16384      // B*S = 8*2048
#define GROUPQ 64
#define SCALING 2.0f

// GEMM tiling
#define BM 128
#define BN 128
#define BK 32
#define KTILES (D_IN / BK)        // 128
#define LDS_HALF (BM * BK * 2)    // 8192 bytes per operand tile

typedef float  f32x4  __attribute__((ext_vector_type(4)));
typedef __bf16 bf16x8 __attribute__((ext_vector_type(8)));
typedef unsigned short ushort8 __attribute__((ext_vector_type(8)));
typedef int    int4v  __attribute__((ext_vector_type(4)));
typedef float  float4v __attribute__((ext_vector_type(4)));

// round-to-nearest-even f32 -> bf16
__device__ __forceinline__ unsigned short f2bf(float f) {
  union { float f; unsigned u; } v; v.f = f;
  unsigned r = v.u + 0x7FFF + ((v.u >> 16) & 1);
  return (unsigned short)(r >> 16);
}

// async global->LDS, 16B per lane (wave-uniform base + lane*16 on LDS side)
#define ASYNC16(g, l)                                                        \
  __builtin_amdgcn_global_load_lds(                                          \
      (const __attribute__((address_space(1))) unsigned int*)(g),            \
      (__attribute__((address_space(3))) unsigned int*)(l), 16, 0, 0)

// ---------------------------------------------------------------- prep: x -> bf16
__global__ __launch_bounds__(256) void prep_x_kernel(const float* __restrict__ x,
                                                     unsigned short* __restrict__ xbf) {
  int i = (blockIdx.x * 256 + threadIdx.x) * 8;
  float4v lo = *(const float4v*)(x + i);
  float4v hi = *(const float4v*)(x + i + 4);
  ushort8 o;
  o[0] = f2bf(lo[0]); o[1] = f2bf(lo[1]); o[2] = f2bf(lo[2]); o[3] = f2bf(lo[3]);
  o[4] = f2bf(hi[0]); o[5] = f2bf(hi[1]); o[6] = f2bf(hi[2]); o[7] = f2bf(hi[3]);
  *(ushort8*)(xbf + i) = o;
}

// ------------------------------------------- prep: W_eff = dequant(codes)+2*delta
__global__ __launch_bounds__(256) void prep_w_kernel(const int* __restrict__ codes,
                                                     const float* __restrict__ scales,
                                                     const float* __restrict__ delta,
                                                     unsigned short* __restrict__ weff) {
  int i = (blockIdx.x * 256 + threadIdx.x) * 8;   // 8 consecutive elems, same group
  int row = i >> 12;          // / D_IN
  int col = i & (D_IN - 1);
  float s = scales[(row << 6) + (col >> 6)];      // 64 groups per row
  int4v   c0 = *(const int4v*)(codes + i);
  int4v   c1 = *(const int4v*)(codes + i + 4);
  float4v d0 = *(const float4v*)(delta + i);
  float4v d1 = *(const float4v*)(delta + i + 4);
  ushort8 o;
  o[0] = f2bf((float)(c0[0] - 8) * s + SCALING * d0[0]);
  o[1] = f2bf((float)(c0[1] - 8) * s + SCALING * d0[1]);
  o[2] = f2bf((float)(c0[2] - 8) * s + SCALING * d0[2]);
  o[3] = f2bf((float)(c0[3] - 8) * s + SCALING * d0[3]);
  o[4] = f2bf((float)(c1[0] - 8) * s + SCALING * d1[0]);
  o[5] = f2bf((float)(c1[1] - 8) * s + SCALING * d1[1]);
  o[6] = f2bf((float)(c1[2] - 8) * s + SCALING * d1[2]);
  o[7] = f2bf((float)(c1[3] - 8) * s + SCALING * d1[3]);
  *(ushort8*)(weff + i) = o;
}

// ---------------------------------------------------------------- main GEMM
// C[M][N] = Xbf[M][K] * Weff[N][K]^T + bias ; 128x128 tile, BK=32, 4 waves.
__global__ __launch_bounds__(256) void gemm_kernel(const unsigned short* __restrict__ xbf,
                                                   const unsigned short* __restrict__ weff,
                                                   const float* __restrict__ bias,
                                                   float* __restrict__ out) {
  __shared__ __align__(16) char lds[2][2 * LDS_HALF];  // [buf][A 8KB | B 8KB]

  const int tid  = threadIdx.x;
  const int bn   = blockIdx.x;      // N tile
  const int bm   = blockIdx.y;      // M tile
  const int wid  = tid >> 6;
  const int lane = tid & 63;
  const int wr   = wid >> 1;        // wave row  (0..1)
  const int wc   = wid & 1;         // wave col  (0..1)
  const int l15  = lane & 15;
  const int l4   = lane >> 4;

  // staging chunks: tile = 512 x 16B chunks; chunk c -> row c>>2, kchunk c&3
  const int c0 = tid, c1 = tid + 256;
  const unsigned short* ga0 = xbf  + (bm * BM + (c0 >> 2)) * D_IN + (c0 & 3) * 8;
  const unsigned short* ga1 = xbf  + (bm * BM + (c1 >> 2)) * D_IN + (c1 & 3) * 8;
  const unsigned short* gb0 = weff + (bn * BN + (c0 >> 2)) * D_IN + (c0 & 3) * 8;
  const unsigned short* gb1 = weff + (bn * BN + (c1 >> 2)) * D_IN + (c1 & 3) * 8;

  f32x4 acc[4][4] = {};

  auto stage = [&](int buf, int kt) {
    const int koff = kt * BK;
    char* base = lds[buf];
    ASYNC16(ga0 + koff, base + c0 * 16);
    ASYNC16(ga1 + koff, base + c1 * 16);
    ASYNC16(gb0 + koff, base + LDS_HALF + c0 * 16);
    ASYNC16(gb1 + koff, base + LDS_HALF + c1 * 16);
  };

  int cur = 0;
  stage(0, 0);
  __syncthreads();   // drains vmcnt(0) -> buf0 ready

  for (int kt = 0; kt < KTILES; ++kt) {
    if (kt + 1 < KTILES) stage(cur ^ 1, kt + 1);

    const char* Ab = lds[cur];
    const char* Bb = lds[cur] + LDS_HALF;
    bf16x8 a[4], b[4];
#pragma unroll
    for (int m = 0; m < 4; ++m)
      a[m] = *(const bf16x8*)(Ab + ((wr * 64 + m * 16 + l15) * BK + l4 * 8) * 2);
#pragma unroll
    for (int n = 0; n < 4; ++n)
      b[n] = *(const bf16x8*)(Bb + ((wc * 64 + n * 16 + l15) * BK + l4 * 8) * 2);

#pragma unroll
    for (int m = 0; m < 4; ++m)
#pragma unroll
      for (int n = 0; n < 4; ++n)
        acc[m][n] = __builtin_amdgcn_mfma_f32_16x16x32_bf16(a[m], b[n], acc[m][n], 0, 0, 0);

    __syncthreads();   // implicit vmcnt(0)+lgkmcnt(0): next buffer staged, this one reusable
    cur ^= 1;
  }

  // epilogue: C/D layout col = lane&15, row = (lane>>4)*4 + j  [m89-verified]
  const int rowbase = bm * BM + wr * 64;
  const int colbase = bn * BN + wc * 64;
  float bias_n[4];
#pragma unroll
  for (int n = 0; n < 4; ++n) bias_n[n] = bias[colbase + n * 16 + l15];

#pragma unroll
  for (int m = 0; m < 4; ++m) {
    const int row0 = rowbase + m * 16 + l4 * 4;
#pragma unroll
    for (int n = 0; n < 4; ++n) {
      const int col = colbase + n * 16 + l15;
#pragma unroll
      for (int j = 0; j < 4; ++j)
        out[(row0 + j) * D_OUT + col] = acc[m][n][j] + bias_n[n];
    }
  }
}

extern "C" void kernel_launch(void* const* d_in, const int* in_sizes, int n_in,
                              void* d_out, int out_size, void* d_ws, size_t ws_size,
                              hipStream_t stream) {
  const float* x      = (const float*)d_in[0];
  const int*   codes  = (const int*)d_in[1];
  const float* scales = (const float*)d_in[2];
  const float* bias   = (const float*)d_in[3];
  const float* delta  = (const float*)d_in[4];
  float* out = (float*)d_out;

  unsigned short* xbf  = (unsigned short*)d_ws;                    // 128 MiB
  unsigned short* weff = xbf + (size_t)MTOT * D_IN;                // +32 MiB

  prep_x_kernel<<<(MTOT * D_IN) / (256 * 8), 256, 0, stream>>>(x, xbf);
  prep_w_kernel<<<(D_OUT * D_IN) / (256 * 8), 256, 0, stream>>>(codes, scales, delta, weff);

  dim3 grid(D_OUT / BN, MTOT / BM);   // (32, 128)
  gemm_kernel<<<grid, 256, 0, stream>>>(xbf, weff, bias, out);
}

// Round 2
// 579.440 us; speedup vs baseline: 1.3728x; 1.3728x over previous
//
#include <hip/hip_runtime.h>
#include <cstdint>

// Problem geometry (fixed by the reference)
#define D_IN   4096
#define D_OUT  4096
#define MTOT   16384      // B*S = 8*2048
#define SCALING 2.0f

// GEMM tiling: 256x256 tile, BK=64, 8 waves (2M x 4N), 8-phase schedule
#define BM 256
#define BN 256
#define BK 64
#define KT (D_IN / BK)    // 64 K-tiles

typedef float  f32x4  __attribute__((ext_vector_type(4)));
typedef __bf16 bf16x8 __attribute__((ext_vector_type(8)));
typedef unsigned short ushort8 __attribute__((ext_vector_type(8)));
typedef int    int4v  __attribute__((ext_vector_type(4)));
typedef float  float4v __attribute__((ext_vector_type(4)));

// round-to-nearest-even f32 -> bf16
__device__ __forceinline__ unsigned short f2bf(float f) {
  union { float f; unsigned u; } v; v.f = f;
  unsigned r = v.u + 0x7FFF + ((v.u >> 16) & 1);
  return (unsigned short)(r >> 16);
}

// async global->LDS, 16B per lane (wave-uniform base + lane*16 on LDS side)
#define ASYNC16(g, l)                                                        \
  __builtin_amdgcn_global_load_lds(                                          \
      (const __attribute__((address_space(1))) unsigned int*)(g),            \
      (__attribute__((address_space(3))) unsigned int*)(l), 16, 0, 0)

#define BAR    __builtin_amdgcn_s_barrier()
#define LGKM0  asm volatile("s_waitcnt lgkmcnt(0)" ::: "memory")
#define VM4    asm volatile("s_waitcnt vmcnt(4)" ::: "memory")
#define VM0    asm volatile("s_waitcnt vmcnt(0)" ::: "memory")

// ---------------------------------------------------------------- prep: x -> bf16
__global__ __launch_bounds__(256) void prep_x_kernel(const float* __restrict__ x,
                                                     unsigned short* __restrict__ xbf) {
  int i = (blockIdx.x * 256 + threadIdx.x) * 8;
  float4v lo = *(const float4v*)(x + i);
  float4v hi = *(const float4v*)(x + i + 4);
  ushort8 o;
  o[0] = f2bf(lo[0]); o[1] = f2bf(lo[1]); o[2] = f2bf(lo[2]); o[3] = f2bf(lo[3]);
  o[4] = f2bf(hi[0]); o[5] = f2bf(hi[1]); o[6] = f2bf(hi[2]); o[7] = f2bf(hi[3]);
  *(ushort8*)(xbf + i) = o;
}

// ------------------------------------------- prep: W_eff = dequant(codes)+2*delta
__global__ __launch_bounds__(256) void prep_w_kernel(const int* __restrict__ codes,
                                                     const float* __restrict__ scales,
                                                     const float* __restrict__ delta,
                                                     unsigned short* __restrict__ weff) {
  int i = (blockIdx.x * 256 + threadIdx.x) * 8;   // 8 consecutive elems, same group
  int row = i >> 12;          // / D_IN
  int col = i & (D_IN - 1);
  float s = scales[(row << 6) + (col >> 6)];      // 64 groups per row
  int4v   c0 = *(const int4v*)(codes + i);
  int4v   c1 = *(const int4v*)(codes + i + 4);
  float4v d0 = *(const float4v*)(delta + i);
  float4v d1 = *(const float4v*)(delta + i + 4);
  ushort8 o;
  o[0] = f2bf((float)(c0[0] - 8) * s + SCALING * d0[0]);
  o[1] = f2bf((float)(c0[1] - 8) * s + SCALING * d0[1]);
  o[2] = f2bf((float)(c0[2] - 8) * s + SCALING * d0[2]);
  o[3] = f2bf((float)(c0[3] - 8) * s + SCALING * d0[3]);
  o[4] = f2bf((float)(c1[0] - 8) * s + SCALING * d1[0]);
  o[5] = f2bf((float)(c1[1] - 8) * s + SCALING * d1[1]);
  o[6] = f2bf((float)(c1[2] - 8) * s + SCALING * d1[2]);
  o[7] = f2bf((float)(c1[3] - 8) * s + SCALING * d1[3]);
  *(ushort8*)(weff + i) = o;
}

// ---------------------------------------------------------------- main GEMM
// C[M][N] = Xbf[M][K] * Weff[N][K]^T + bias
// 256x256 tile, BK=64, 512 threads (8 waves: wr=wid>>2, wc=wid&3), 8-phase.
// LDS slots per buffer: [A0 rows0-127][A1 rows128-255][B0][B1], each [128][64] bf16,
// XOR-swizzled: byte ^= ((row&7)<<4) (inverse-swizzled source, swizzled ds_read).
//
// Staging: per half-tile 2 x global_load_lds(16B) per thread.
//   STAGE A(g+1) at P0/P1 into buf^1 (A slots free after prev group's P2 reads);
//   STAGE B(g+2) at P2/P3 into buf   (B slots last read at this group's P1).
// vmcnt(4) at end of each group: drains tile g+1, leaves B(g+2)'s 4 loads in flight.

#define STAGE_A(buf_, kt_, h_) do {                                          \
    char* d_ = &lds[buf_][h_][0] + tid * 16;                                 \
    const unsigned short* s_ = gA + (size_t)(h_) * 128 * D_IN + (kt_) * 64;  \
    ASYNC16(s_, d_);                                                         \
    ASYNC16(s_ + 64 * D_IN, d_ + 8192);                                      \
  } while (0)

#define STAGE_B(buf_, kt_, h_) do {                                          \
    char* d_ = &lds[buf_][2 + (h_)][0] + tid * 16;                           \
    const unsigned short* s_ = gB + (size_t)(h_) * 128 * D_IN + (kt_) * 64;  \
    ASYNC16(s_, d_);                                                         \
    ASYNC16(s_ + 64 * D_IN, d_ + 8192);                                      \
  } while (0)

#define RD_A(buf_, mh_, dst_) do {                                           \
    _Pragma("unroll")                                                        \
    for (int m2 = 0; m2 < 4; ++m2) {                                         \
      const char* p_ = &lds[buf_][wr][0] + ((mh_)*4 + m2) * 2048 + rowb;     \
      dst_[m2][0] = *(const bf16x8*)(p_ + koff0);                            \
      dst_[m2][1] = *(const bf16x8*)(p_ + koff1);                            \
    } } while (0)

#define RD_B(buf_, nh_, dst_) do {                                           \
    _Pragma("unroll")                                                        \
    for (int n2 = 0; n2 < 2; ++n2) {                                         \
      const char* p_ = &lds[buf_][2 + (wc >> 1)][0] + (wc & 1) * 8192 +      \
                       (nh_) * 4096 + n2 * 2048 + rowb;                      \
      dst_[n2][0] = *(const bf16x8*)(p_ + koff0);                            \
      dst_[n2][1] = *(const bf16x8*)(p_ + koff1);                            \
    } } while (0)

#define MM(afr_, bfr_, mh_, nh_) do {                                        \
    __builtin_amdgcn_s_setprio(1);                                           \
    _Pragma("unroll")                                                        \
    for (int m2 = 0; m2 < 4; ++m2) {                                         \
      _Pragma("unroll")                                                      \
      for (int n2 = 0; n2 < 2; ++n2) {                                       \
        acc[(mh_)*4 + m2][(nh_)*2 + n2] = __builtin_amdgcn_mfma_f32_16x16x32_bf16( \
            afr_[m2][0], bfr_[n2][0], acc[(mh_)*4 + m2][(nh_)*2 + n2], 0, 0, 0);   \
        acc[(mh_)*4 + m2][(nh_)*2 + n2] = __builtin_amdgcn_mfma_f32_16x16x32_bf16( \
            afr_[m2][1], bfr_[n2][1], acc[(mh_)*4 + m2][(nh_)*2 + n2], 0, 0, 0);   \
      } }                                                                    \
    __builtin_amdgcn_s_setprio(0);                                           \
  } while (0)

__global__ __launch_bounds__(512, 2) void gemm8_kernel(const unsigned short* __restrict__ xbf,
                                                       const unsigned short* __restrict__ weff,
                                                       const float* __restrict__ bias,
                                                       float* __restrict__ out) {
  __shared__ __attribute__((aligned(1024))) char lds[2][4][16384];  // 128 KiB

  const int tid  = threadIdx.x;
  const int lane = tid & 63;
  const int wid  = tid >> 6;
  const int wr   = wid >> 2;        // 0..1  (M half)
  const int wc   = wid & 3;         // 0..3  (N quarter)

  // bijective XCD swizzle: 1024 wgs, 8 XCDs -> each XCD gets 8 M-rows x 16 N-cols
  const int id  = blockIdx.x;
  const int nid = (id & 7) * 128 + (id >> 3);
  const int tn  = nid & 15;         // N tile (16)
  const int tm  = nid >> 4;         // M tile (64)

  // ds_read lane offsets (swizzled): addr = row*128 + ((kk*64 + (l>>4)*16) ^ ((l&7)<<4))
  const int rowb  = (lane & 15) * 128;
  const int kx    = (lane & 7) << 4;
  const int koff0 = (((lane >> 4) * 16) ^ kx);
  const int koff1 = ((64 + (lane >> 4) * 16) ^ kx);

  // staging lane offsets (inverse-swizzled source)
  const int sr = tid >> 3;                        // row within 64-row chunk
  const int ke = ((tid & 7) ^ (sr & 7)) * 8;      // permuted k-element offset
  const unsigned short* gA = xbf  + (size_t)(tm * BM + sr) * D_IN + ke;
  const unsigned short* gB = weff + (size_t)(tn * BN + sr) * D_IN + ke;

  f32x4 acc[8][4] = {};
  bf16x8 a[4][2], b0[2][2], b1[2][2];

  // prologue: tile 0 (A+B) -> buf0 ; B of tile 1 -> buf1
  STAGE_A(0, 0, 0); STAGE_A(0, 0, 1);
  STAGE_B(0, 0, 0); STAGE_B(0, 0, 1);
  STAGE_B(1, 1, 0); STAGE_B(1, 1, 1);
  VM4;              // tile 0 landed; B(1) may stay in flight
  BAR;

  int buf = 0;
  for (int g = 0; g < KT; ++g) {
    // ---- P0: quadrant (mh0, nh0)
    RD_A(buf, 0, a); RD_B(buf, 0, b0);               // 12 ds_read_b128
    if (g + 1 < KT) STAGE_A(buf ^ 1, g + 1, 0);
    BAR; LGKM0;
    MM(a, b0, 0, 0);
    BAR;
    // ---- P1: quadrant (mh0, nh1)
    RD_B(buf, 1, b1);                                // 4 ds_read_b128
    if (g + 1 < KT) STAGE_A(buf ^ 1, g + 1, 1);
    BAR; LGKM0;
    MM(a, b1, 0, 1);
    BAR;
    // ---- P2: quadrant (mh1, nh0)
    RD_A(buf, 1, a);                                 // 8 ds_read_b128
    if (g + 2 < KT) STAGE_B(buf, g + 2, 0);
    BAR; LGKM0;
    MM(a, b0, 1, 0);
    BAR;
    // ---- P3: quadrant (mh1, nh1)
    if (g + 2 < KT) STAGE_B(buf, g + 2, 1);
    BAR; LGKM0;
    MM(a, b1, 1, 1);
    if (g < KT - 2) { VM4; } else { VM0; }           // counted drain, never 0 mid-loop
    BAR;
    buf ^= 1;
  }

  // epilogue: C/D layout col = lane&15, row = (lane>>4)*4 + j  [m89-verified]
  const int row0 = tm * BM + wr * 128 + (lane >> 4) * 4;
  const int col0 = tn * BN + wc * 64 + (lane & 15);
#pragma unroll
  for (int n = 0; n < 4; ++n) {
    const int col = col0 + n * 16;
    const float bv = bias[col];
#pragma unroll
    for (int m = 0; m < 8; ++m) {
      const int r = row0 + m * 16;
#pragma unroll
      for (int j = 0; j < 4; ++j)
        out[(size_t)(r + j) * D_OUT + col] = acc[m][n][j] + bv;
    }
  }
}

extern "C" void kernel_launch(void* const* d_in, const int* in_sizes, int n_in,
                              void* d_out, int out_size, void* d_ws, size_t ws_size,
                              hipStream_t stream) {
  const float* x      = (const float*)d_in[0];
  const int*   codes  = (const int*)d_in[1];
  const float* scales = (const float*)d_in[2];
  const float* bias   = (const float*)d_in[3];
  const float* delta  = (const float*)d_in[4];
  float* out = (float*)d_out;

  unsigned short* xbf  = (unsigned short*)d_ws;                    // 128 MiB
  unsigned short* weff = xbf + (size_t)MTOT * D_IN;                // +32 MiB

  prep_x_kernel<<<(MTOT * D_IN) / (256 * 8), 256, 0, stream>>>(x, xbf);
  prep_w_kernel<<<(D_OUT * D_IN) / (256 * 8), 256, 0, stream>>>(codes, scales, delta, weff);

  gemm8_kernel<<<(MTOT / BM) * (D_OUT / BN), 512, 0, stream>>>(xbf, weff, bias, out);
}